// Round 1
// baseline (3088.054 us; speedup 1.0000x reference)
//
#include <hip/hip_runtime.h>

#define IN_C 256
#define H1 8
#define C1 32
#define F1 256   // H1*C1
#define OC 16
#define NEG 0.2f

// ---------------- L1 GEMM: xl1[M,F1] = x[M,IN_C] @ W1[IN_C,F1] ----------------
__global__ __launch_bounds__(256) void k_sgemm64(const float* __restrict__ A,
                                                 const float* __restrict__ B,
                                                 float* __restrict__ C,
                                                 int M, int N, int K)
{
    __shared__ float As[16][64];
    __shared__ float Bs[16][64];
    const int tid  = threadIdx.x;
    const int bm   = blockIdx.x * 64;
    const int bn   = blockIdx.y * 64;
    const int tcol = (tid & 15) * 4;
    const int trow = (tid >> 4) * 4;
    const int arow = tid >> 2;
    const int ak   = (tid & 3) * 4;
    const int bk   = tid >> 4;
    const int bcol = (tid & 15) * 4;
    float acc[4][4] = {};
    for (int k0 = 0; k0 < K; k0 += 16) {
        float4 av = make_float4(0.f, 0.f, 0.f, 0.f);
        int gr = bm + arow;
        if (gr < M) av = *(const float4*)(A + (size_t)gr * K + k0 + ak);
        As[ak+0][arow] = av.x; As[ak+1][arow] = av.y;
        As[ak+2][arow] = av.z; As[ak+3][arow] = av.w;
        *(float4*)&Bs[bk][bcol] = *(const float4*)(B + (size_t)(k0 + bk) * N + bn + bcol);
        __syncthreads();
#pragma unroll
        for (int kk = 0; kk < 16; ++kk) {
            float a0 = As[kk][trow+0], a1 = As[kk][trow+1];
            float a2 = As[kk][trow+2], a3 = As[kk][trow+3];
            float b0 = Bs[kk][tcol+0], b1 = Bs[kk][tcol+1];
            float b2 = Bs[kk][tcol+2], b3 = Bs[kk][tcol+3];
            acc[0][0] += a0*b0; acc[0][1] += a0*b1; acc[0][2] += a0*b2; acc[0][3] += a0*b3;
            acc[1][0] += a1*b0; acc[1][1] += a1*b1; acc[1][2] += a1*b2; acc[1][3] += a1*b3;
            acc[2][0] += a2*b0; acc[2][1] += a2*b1; acc[2][2] += a2*b2; acc[2][3] += a2*b3;
            acc[3][0] += a3*b0; acc[3][1] += a3*b1; acc[3][2] += a3*b2; acc[3][3] += a3*b3;
        }
        __syncthreads();
    }
#pragma unroll
    for (int i = 0; i < 4; ++i) {
        int gr = bm + trow + i;
        if (gr < M) {
            float4 o = make_float4(acc[i][0], acc[i][1], acc[i][2], acc[i][3]);
            *(float4*)(C + (size_t)gr * N + bn + tcol) = o;
        }
    }
}

// ---------------- L1 attention coefficients: a_src/a_dst [N,H1] ----------------
__global__ __launch_bounds__(256) void k_att1(const float* __restrict__ xl,
                                              const float* __restrict__ att_s,
                                              const float* __restrict__ att_d,
                                              float* __restrict__ asrc,
                                              float* __restrict__ adst, int N)
{
    int idx = blockIdx.x * 256 + threadIdx.x;
    if (idx >= N * H1) return;
    int i = idx >> 3, h = idx & 7;
    const float* xr = xl + (size_t)i * F1 + h * C1;
    const float* s  = att_s + h * C1;
    const float* d  = att_d + h * C1;
    float s1 = 0.f, s2 = 0.f;
#pragma unroll
    for (int c = 0; c < C1; ++c) { float v = xr[c]; s1 += v * s[c]; s2 += v * d[c]; }
    asrc[idx] = s1; adst[idx] = s2;
}

// ---------------- L1 self-loop init: den1 = w_self, out_u = w_self*xl ----------------
__global__ __launch_bounds__(256) void k_init1(const float* __restrict__ xl,
                                               const float* __restrict__ asrc,
                                               const float* __restrict__ adst,
                                               float* __restrict__ den,
                                               float* __restrict__ outu, int N)
{
    int lane = threadIdx.x & 63;
    int node = blockIdx.x * 4 + (threadIdx.x >> 6);
    if (node >= N) return;
    int h = lane >> 3;
    float e = asrc[(size_t)node * H1 + h] + adst[(size_t)node * H1 + h];
    e = e >= 0.f ? e : NEG * e;
    float w = __expf(e);
    if ((lane & 7) == 0) den[(size_t)node * H1 + h] = w;
    int cb = lane * 4;
    float4 xv = *(const float4*)(xl + (size_t)node * F1 + cb);
    float4 o  = make_float4(w * xv.x, w * xv.y, w * xv.z, w * xv.w);
    *(float4*)(outu + (size_t)node * F1 + cb) = o;
}

// ---------------- L1 edge pass: one wave per edge ----------------
__global__ __launch_bounds__(256) void k_edge1(const int* __restrict__ ei,
                                               const float* __restrict__ xl,
                                               const float* __restrict__ asrc,
                                               const float* __restrict__ adst,
                                               float* __restrict__ den,
                                               float* __restrict__ outu, int E)
{
    int lane = threadIdx.x & 63;
    int e = blockIdx.x * 4 + (threadIdx.x >> 6);
    if (e >= E) return;
    int s = ei[e];
    int d = ei[E + e];
    int h = lane >> 3;
    float ev = asrc[(size_t)s * H1 + h] + adst[(size_t)d * H1 + h];
    ev = ev >= 0.f ? ev : NEG * ev;
    float w = __expf(ev);
    if ((lane & 7) == 0) atomicAdd(&den[(size_t)d * H1 + h], w);
    int cb = lane * 4;
    float4 xv = *(const float4*)(xl + (size_t)s * F1 + cb);
    float* od = outu + (size_t)d * F1 + cb;
    atomicAdd(od + 0, w * xv.x);
    atomicAdd(od + 1, w * xv.y);
    atomicAdd(od + 2, w * xv.z);
    atomicAdd(od + 3, w * xv.w);
}

// ---------------- L1 normalize + bias + ReLU (in place) ----------------
__global__ __launch_bounds__(256) void k_norm1(float* __restrict__ outu,
                                               const float* __restrict__ den,
                                               const float* __restrict__ bias, int N)
{
    int idx = blockIdx.x * 256 + threadIdx.x;
    if (idx >= N * F1) return;
    int i = idx >> 8, c = idx & 255, h = c >> 5;
    float v = outu[idx] / (den[(size_t)i * H1 + h] + 1e-16f) + bias[c];
    outu[idx] = fmaxf(v, 0.f);
}

// ---------------- L2 GEMM: xl2[N,OC] = h[N,F1] @ W2[F1,OC] ----------------
__global__ __launch_bounds__(256) void k_gemm2(const float* __restrict__ Hm,
                                               const float* __restrict__ W2,
                                               float* __restrict__ xl2, int N)
{
    __shared__ float Ws[F1 * OC];   // 16 KB
    __shared__ float Hs[16 * F1];   // 16 KB
    int tid = threadIdx.x;
    int base = blockIdx.x * 16;
    for (int idx = tid; idx < F1 * OC; idx += 256) Ws[idx] = W2[idx];
    for (int idx = tid; idx < 16 * F1; idx += 256) {
        int r = idx >> 8, k = idx & 255;
        int gr = base + r;
        Hs[idx] = (gr < N) ? Hm[(size_t)gr * F1 + k] : 0.f;
    }
    __syncthreads();
    int r = tid >> 4, c = tid & 15;
    float acc = 0.f;
#pragma unroll 8
    for (int k = 0; k < F1; ++k) acc += Hs[r * F1 + k] * Ws[k * OC + c];
    int gr = base + r;
    if (gr < N) xl2[(size_t)gr * OC + c] = acc;
}

// ---------------- L2 attention coefficients ----------------
__global__ __launch_bounds__(256) void k_att2(const float* __restrict__ xl2,
                                              const float* __restrict__ att_s,
                                              const float* __restrict__ att_d,
                                              float* __restrict__ asrc,
                                              float* __restrict__ adst, int N)
{
    int i = blockIdx.x * 256 + threadIdx.x;
    if (i >= N) return;
    float s1 = 0.f, s2 = 0.f;
#pragma unroll
    for (int c = 0; c < OC; ++c) {
        float v = xl2[(size_t)i * OC + c];
        s1 += v * att_s[c]; s2 += v * att_d[c];
    }
    asrc[i] = s1; adst[i] = s2;
}

// ---------------- L2 self-loop init ----------------
__global__ __launch_bounds__(256) void k_init2(const float* __restrict__ xl2,
                                               const float* __restrict__ asrc,
                                               const float* __restrict__ adst,
                                               float* __restrict__ den,
                                               float* __restrict__ outu, int N)
{
    int sub = threadIdx.x & 15;
    int node = blockIdx.x * 16 + (threadIdx.x >> 4);
    if (node >= N) return;
    float e = asrc[node] + adst[node];
    e = e >= 0.f ? e : NEG * e;
    float w = __expf(e);
    if (sub == 0) den[node] = w;
    outu[(size_t)node * OC + sub] = w * xl2[(size_t)node * OC + sub];
}

// ---------------- L2 edge pass: 16 lanes per edge ----------------
__global__ __launch_bounds__(256) void k_edge2(const int* __restrict__ ei,
                                               const float* __restrict__ xl2,
                                               const float* __restrict__ asrc,
                                               const float* __restrict__ adst,
                                               float* __restrict__ den,
                                               float* __restrict__ outu, int E)
{
    int sub = threadIdx.x & 15;
    int e = blockIdx.x * 16 + (threadIdx.x >> 4);
    if (e >= E) return;
    int s = ei[e];
    int d = ei[E + e];
    float ev = asrc[s] + adst[d];
    ev = ev >= 0.f ? ev : NEG * ev;
    float w = __expf(ev);
    if (sub == 0) atomicAdd(&den[d], w);
    atomicAdd(&outu[(size_t)d * OC + sub], w * xl2[(size_t)s * OC + sub]);
}

// ---------------- finalize: normalize + bias + log_softmax ----------------
__global__ __launch_bounds__(256) void k_fin(const float* __restrict__ outu,
                                             const float* __restrict__ den,
                                             const float* __restrict__ bias,
                                             float* __restrict__ out, int N)
{
    int i = blockIdx.x * 256 + threadIdx.x;
    if (i >= N) return;
    float v[OC];
    float dn = den[i] + 1e-16f;
    float m = -1e30f;
#pragma unroll
    for (int c = 0; c < OC; ++c) {
        v[c] = outu[(size_t)i * OC + c] / dn + bias[c];
        m = fmaxf(m, v[c]);
    }
    float ssum = 0.f;
#pragma unroll
    for (int c = 0; c < OC; ++c) ssum += __expf(v[c] - m);
    float ls = logf(ssum);
#pragma unroll
    for (int c = 0; c < OC; ++c) out[(size_t)i * OC + c] = v[c] - m - ls;
}

extern "C" void kernel_launch(void* const* d_in, const int* in_sizes, int n_in,
                              void* d_out, int out_size, void* d_ws, size_t ws_size,
                              hipStream_t stream)
{
    const float* x   = (const float*)d_in[0];
    const int*   ei  = (const int*)d_in[1];
    const float* W1  = (const float*)d_in[2];
    const float* as1 = (const float*)d_in[3];
    const float* ad1 = (const float*)d_in[4];
    const float* b1  = (const float*)d_in[5];
    const float* W2  = (const float*)d_in[6];
    const float* as2 = (const float*)d_in[7];
    const float* ad2 = (const float*)d_in[8];
    const float* b2  = (const float*)d_in[9];
    float* out = (float*)d_out;

    const int N = in_sizes[0] / IN_C;   // 50000
    const int E = in_sizes[1] / 2;      // 800000

    float* ws    = (float*)d_ws;
    float* xl1   = ws;                         // N*F1
    float* hbuf  = xl1 + (size_t)N * F1;       // N*F1 (out1_u, then h in place)
    float* asrc1 = hbuf + (size_t)N * F1;      // N*H1
    float* adst1 = asrc1 + (size_t)N * H1;     // N*H1
    float* den1  = adst1 + (size_t)N * H1;     // N*H1
    float* xl2   = den1 + (size_t)N * H1;      // N*OC
    float* asrc2 = xl2 + (size_t)N * OC;       // N
    float* adst2 = asrc2 + N;                  // N
    float* den2  = adst2 + N;                  // N
    float* out2u = den2 + N;                   // N*OC

    // ---- layer 1 ----
    k_sgemm64<<<dim3((N + 63) / 64, F1 / 64), 256, 0, stream>>>(x, W1, xl1, N, F1, IN_C);
    k_att1<<<(N * H1 + 255) / 256, 256, 0, stream>>>(xl1, as1, ad1, asrc1, adst1, N);
    k_init1<<<(N + 3) / 4, 256, 0, stream>>>(xl1, asrc1, adst1, den1, hbuf, N);
    k_edge1<<<(E + 3) / 4, 256, 0, stream>>>(ei, xl1, asrc1, adst1, den1, hbuf, E);
    k_norm1<<<(N * F1 + 255) / 256, 256, 0, stream>>>(hbuf, den1, b1, N);

    // ---- layer 2 ----
    k_gemm2<<<(N + 15) / 16, 256, 0, stream>>>(hbuf, W2, xl2, N);
    k_att2<<<(N + 255) / 256, 256, 0, stream>>>(xl2, as2, ad2, asrc2, adst2, N);
    k_init2<<<(N + 15) / 16, 256, 0, stream>>>(xl2, asrc2, adst2, den2, out2u, N);
    k_edge2<<<(E + 15) / 16, 256, 0, stream>>>(ei, xl2, asrc2, adst2, den2, out2u, E);
    k_fin<<<(N + 255) / 256, 256, 0, stream>>>(out2u, den2, b2, out, N);
}

// Round 2
// 553.352 us; speedup vs baseline: 5.5806x; 5.5806x over previous
//
#include <hip/hip_runtime.h>

#define IN_C 256
#define H1 8
#define C1 32
#define F1 256   // H1*C1
#define OC 16
#define NEG 0.2f

// ---------------- L1 GEMM: xl1[M,F1] = x[M,IN_C] @ W1[IN_C,F1] ----------------
__global__ __launch_bounds__(256) void k_sgemm64(const float* __restrict__ A,
                                                 const float* __restrict__ B,
                                                 float* __restrict__ C,
                                                 int M, int N, int K)
{
    __shared__ float As[16][64];
    __shared__ float Bs[16][64];
    const int tid  = threadIdx.x;
    const int bm   = blockIdx.x * 64;
    const int bn   = blockIdx.y * 64;
    const int tcol = (tid & 15) * 4;
    const int trow = (tid >> 4) * 4;
    const int arow = tid >> 2;
    const int ak   = (tid & 3) * 4;
    const int bk   = tid >> 4;
    const int bcol = (tid & 15) * 4;
    float acc[4][4] = {};
    for (int k0 = 0; k0 < K; k0 += 16) {
        float4 av = make_float4(0.f, 0.f, 0.f, 0.f);
        int gr = bm + arow;
        if (gr < M) av = *(const float4*)(A + (size_t)gr * K + k0 + ak);
        As[ak+0][arow] = av.x; As[ak+1][arow] = av.y;
        As[ak+2][arow] = av.z; As[ak+3][arow] = av.w;
        *(float4*)&Bs[bk][bcol] = *(const float4*)(B + (size_t)(k0 + bk) * N + bn + bcol);
        __syncthreads();
#pragma unroll
        for (int kk = 0; kk < 16; ++kk) {
            float a0 = As[kk][trow+0], a1 = As[kk][trow+1];
            float a2 = As[kk][trow+2], a3 = As[kk][trow+3];
            float b0 = Bs[kk][tcol+0], b1 = Bs[kk][tcol+1];
            float b2 = Bs[kk][tcol+2], b3 = Bs[kk][tcol+3];
            acc[0][0] += a0*b0; acc[0][1] += a0*b1; acc[0][2] += a0*b2; acc[0][3] += a0*b3;
            acc[1][0] += a1*b0; acc[1][1] += a1*b1; acc[1][2] += a1*b2; acc[1][3] += a1*b3;
            acc[2][0] += a2*b0; acc[2][1] += a2*b1; acc[2][2] += a2*b2; acc[2][3] += a2*b3;
            acc[3][0] += a3*b0; acc[3][1] += a3*b1; acc[3][2] += a3*b2; acc[3][3] += a3*b3;
        }
        __syncthreads();
    }
#pragma unroll
    for (int i = 0; i < 4; ++i) {
        int gr = bm + trow + i;
        if (gr < M) {
            float4 o = make_float4(acc[i][0], acc[i][1], acc[i][2], acc[i][3]);
            *(float4*)(C + (size_t)gr * N + bn + tcol) = o;
        }
    }
}

// ---------------- L1 attention coefficients: a_src/a_dst [N,H1] ----------------
__global__ __launch_bounds__(256) void k_att1(const float* __restrict__ xl,
                                              const float* __restrict__ att_s,
                                              const float* __restrict__ att_d,
                                              float* __restrict__ asrc,
                                              float* __restrict__ adst, int N)
{
    int idx = blockIdx.x * 256 + threadIdx.x;
    if (idx >= N * H1) return;
    int i = idx >> 3, h = idx & 7;
    const float* xr = xl + (size_t)i * F1 + h * C1;
    const float* s  = att_s + h * C1;
    const float* d  = att_d + h * C1;
    float s1 = 0.f, s2 = 0.f;
#pragma unroll
    for (int c = 0; c < C1; ++c) { float v = xr[c]; s1 += v * s[c]; s2 += v * d[c]; }
    asrc[idx] = s1; adst[idx] = s2;
}

// ---------------- CSR build ----------------
__global__ __launch_bounds__(256) void k_zero(int* __restrict__ p, int n)
{
    int i = blockIdx.x * 256 + threadIdx.x;
    if (i < n) p[i] = 0;
}

__global__ __launch_bounds__(256) void k_hist(const int* __restrict__ ei,
                                              int* __restrict__ cnt, int E)
{
    int e = blockIdx.x * 256 + threadIdx.x;
    if (e < E) atomicAdd(&cnt[ei[E + e]], 1);
}

// single-workgroup exclusive scan, 4 elems/thread/chunk
__global__ __launch_bounds__(256) void k_scan(const int* __restrict__ cnt,
                                              int* __restrict__ rp, int N)
{
    __shared__ int wsum[4];
    __shared__ int carry_s;
    int lane = threadIdx.x & 63, wid = threadIdx.x >> 6;
    if (threadIdx.x == 0) { carry_s = 0; rp[0] = 0; }
    __syncthreads();
    for (int base = 0; base < N; base += 1024) {
        int i0 = base + threadIdx.x * 4;
        int v[4];
#pragma unroll
        for (int k = 0; k < 4; ++k) { int i = i0 + k; v[k] = (i < N) ? cnt[i] : 0; }
        int s = v[0] + v[1] + v[2] + v[3];
        int incl = s;
#pragma unroll
        for (int off = 1; off < 64; off <<= 1) {
            int t = __shfl_up(incl, off, 64);
            if (lane >= off) incl += t;
        }
        if (lane == 63) wsum[wid] = incl;
        __syncthreads();
        int wpre = 0;
        for (int w = 0; w < wid; ++w) wpre += wsum[w];
        int carry = carry_s;
        int run = carry + wpre + incl - s;   // exclusive prefix for this thread
#pragma unroll
        for (int k = 0; k < 4; ++k) {
            int i = i0 + k;
            run += v[k];
            if (i < N) rp[i + 1] = run;
        }
        __syncthreads();
        if (threadIdx.x == 255) carry_s = carry + wpre + incl;
        __syncthreads();
    }
}

__global__ __launch_bounds__(256) void k_scatter(const int* __restrict__ ei,
                                                 const int* __restrict__ rp,
                                                 int* __restrict__ cur,
                                                 int* __restrict__ ssrc, int E)
{
    int e = blockIdx.x * 256 + threadIdx.x;
    if (e >= E) return;
    int s = ei[e];
    int d = ei[E + e];
    int pos = rp[d] + atomicAdd(&cur[d], 1);
    ssrc[pos] = s;
}

// ---------------- L1 gather: wave per node, fuses init+edge+norm+bias+ReLU ----------------
__global__ __launch_bounds__(256) void k_gather1(const int* __restrict__ rp,
                                                 const int* __restrict__ ssrc,
                                                 const float* __restrict__ xl,
                                                 const float* __restrict__ asrc,
                                                 const float* __restrict__ adst,
                                                 const float* __restrict__ bias,
                                                 float* __restrict__ hout, int N)
{
    int lane = threadIdx.x & 63;
    int node = blockIdx.x * 4 + (threadIdx.x >> 6);
    if (node >= N) return;
    int h  = lane >> 3;     // head for this lane's 4 channels
    int cb = lane * 4;
    float ad = adst[(size_t)node * H1 + h];
    // self-loop
    float e = asrc[(size_t)node * H1 + h] + ad;
    e = e >= 0.f ? e : NEG * e;
    float w = __expf(e);
    float4 xv = *(const float4*)(xl + (size_t)node * F1 + cb);
    float ax = w * xv.x, ay = w * xv.y, az = w * xv.z, aw = w * xv.w;
    float den = w;
    int jb = rp[node], je = rp[node + 1];
    for (int j = jb; j < je; ++j) {
        int s = ssrc[j];
        float ev = asrc[(size_t)s * H1 + h] + ad;
        ev = ev >= 0.f ? ev : NEG * ev;
        float wv = __expf(ev);
        float4 sv = *(const float4*)(xl + (size_t)s * F1 + cb);
        ax += wv * sv.x; ay += wv * sv.y; az += wv * sv.z; aw += wv * sv.w;
        den += wv;
    }
    float inv = 1.f / (den + 1e-16f);
    float4 bv = *(const float4*)(bias + cb);
    float4 o;
    o.x = fmaxf(ax * inv + bv.x, 0.f);
    o.y = fmaxf(ay * inv + bv.y, 0.f);
    o.z = fmaxf(az * inv + bv.z, 0.f);
    o.w = fmaxf(aw * inv + bv.w, 0.f);
    *(float4*)(hout + (size_t)node * F1 + cb) = o;
}

// ---------------- L2 GEMM: xl2[N,OC] = h[N,F1] @ W2[F1,OC] ----------------
__global__ __launch_bounds__(256) void k_gemm2(const float* __restrict__ Hm,
                                               const float* __restrict__ W2,
                                               float* __restrict__ xl2, int N)
{
    __shared__ float Ws[F1 * OC];   // 16 KB
    __shared__ float Hs[16 * F1];   // 16 KB
    int tid = threadIdx.x;
    int base = blockIdx.x * 16;
    for (int idx = tid; idx < F1 * OC; idx += 256) Ws[idx] = W2[idx];
    for (int idx = tid; idx < 16 * F1; idx += 256) {
        int r = idx >> 8, k = idx & 255;
        int gr = base + r;
        Hs[idx] = (gr < N) ? Hm[(size_t)gr * F1 + k] : 0.f;
    }
    __syncthreads();
    int r = tid >> 4, c = tid & 15;
    float acc = 0.f;
#pragma unroll 8
    for (int k = 0; k < F1; ++k) acc += Hs[r * F1 + k] * Ws[k * OC + c];
    int gr = base + r;
    if (gr < N) xl2[(size_t)gr * OC + c] = acc;
}

// ---------------- L2 attention coefficients ----------------
__global__ __launch_bounds__(256) void k_att2(const float* __restrict__ xl2,
                                              const float* __restrict__ att_s,
                                              const float* __restrict__ att_d,
                                              float* __restrict__ asrc,
                                              float* __restrict__ adst, int N)
{
    int i = blockIdx.x * 256 + threadIdx.x;
    if (i >= N) return;
    float s1 = 0.f, s2 = 0.f;
#pragma unroll
    for (int c = 0; c < OC; ++c) {
        float v = xl2[(size_t)i * OC + c];
        s1 += v * att_s[c]; s2 += v * att_d[c];
    }
    asrc[i] = s1; adst[i] = s2;
}

// ---------------- L2 gather: 16 lanes per node, fuses init+edge+norm+bias+log_softmax ----------------
__global__ __launch_bounds__(256) void k_gather2(const int* __restrict__ rp,
                                                 const int* __restrict__ ssrc,
                                                 const float* __restrict__ xl2,
                                                 const float* __restrict__ asrc,
                                                 const float* __restrict__ adst,
                                                 const float* __restrict__ bias,
                                                 float* __restrict__ out, int N)
{
    int sub  = threadIdx.x & 15;
    int node = blockIdx.x * 16 + (threadIdx.x >> 4);
    if (node >= N) return;
    float ad = adst[node];
    float e = asrc[node] + ad;
    e = e >= 0.f ? e : NEG * e;
    float w = __expf(e);
    float acc = w * xl2[(size_t)node * OC + sub];
    float den = w;
    int jb = rp[node], je = rp[node + 1];
    for (int j = jb; j < je; ++j) {
        int s = ssrc[j];
        float ev = asrc[s] + ad;
        ev = ev >= 0.f ? ev : NEG * ev;
        float wv = __expf(ev);
        acc += wv * xl2[(size_t)s * OC + sub];
        den += wv;
    }
    float v = acc / (den + 1e-16f) + bias[sub];
    float m = v;
#pragma unroll
    for (int o = 1; o < 16; o <<= 1) m = fmaxf(m, __shfl_xor(m, o, 16));
    float ex = __expf(v - m);
    float ss = ex;
#pragma unroll
    for (int o = 1; o < 16; o <<= 1) ss += __shfl_xor(ss, o, 16);
    out[(size_t)node * OC + sub] = v - m - logf(ss);
}

extern "C" void kernel_launch(void* const* d_in, const int* in_sizes, int n_in,
                              void* d_out, int out_size, void* d_ws, size_t ws_size,
                              hipStream_t stream)
{
    const float* x   = (const float*)d_in[0];
    const int*   ei  = (const int*)d_in[1];
    const float* W1  = (const float*)d_in[2];
    const float* as1 = (const float*)d_in[3];
    const float* ad1 = (const float*)d_in[4];
    const float* b1  = (const float*)d_in[5];
    const float* W2  = (const float*)d_in[6];
    const float* as2 = (const float*)d_in[7];
    const float* ad2 = (const float*)d_in[8];
    const float* b2  = (const float*)d_in[9];
    float* out = (float*)d_out;

    const int N = in_sizes[0] / IN_C;   // 50000
    const int E = in_sizes[1] / 2;      // 800000

    float* ws    = (float*)d_ws;
    float* xl1   = ws;                          // N*F1
    float* hbuf  = xl1 + (size_t)N * F1;        // N*F1
    float* asrc1 = hbuf + (size_t)N * F1;       // N*H1
    float* adst1 = asrc1 + (size_t)N * H1;      // N*H1
    float* xl2   = adst1 + (size_t)N * H1;      // N*OC
    float* asrc2 = xl2 + (size_t)N * OC;        // N
    float* adst2 = asrc2 + N;                   // N
    int*   rp    = (int*)(adst2 + N);           // N+1
    int*   cnt   = rp + (N + 1);                // N   (cnt and cur adjacent -> one zeroing)
    int*   cur   = cnt + N;                     // N
    int*   ssrc  = cur + N;                     // E

    // ---- CSR build (dst-sorted src ids), reused by both layers ----
    k_zero<<<(2 * N + 255) / 256, 256, 0, stream>>>(cnt, 2 * N);
    k_hist<<<(E + 255) / 256, 256, 0, stream>>>(ei, cnt, E);
    k_scan<<<1, 256, 0, stream>>>(cnt, rp, N);
    k_scatter<<<(E + 255) / 256, 256, 0, stream>>>(ei, rp, cur, ssrc, E);

    // ---- layer 1 ----
    k_sgemm64<<<dim3((N + 63) / 64, F1 / 64), 256, 0, stream>>>(x, W1, xl1, N, F1, IN_C);
    k_att1<<<(N * H1 + 255) / 256, 256, 0, stream>>>(xl1, as1, ad1, asrc1, adst1, N);
    k_gather1<<<(N + 3) / 4, 256, 0, stream>>>(rp, ssrc, xl1, asrc1, adst1, b1, hbuf, N);

    // ---- layer 2 ----
    k_gemm2<<<(N + 15) / 16, 256, 0, stream>>>(hbuf, W2, xl2, N);
    k_att2<<<(N + 255) / 256, 256, 0, stream>>>(xl2, as2, ad2, asrc2, adst2, N);
    k_gather2<<<(N + 15) / 16, 256, 0, stream>>>(rp, ssrc, xl2, asrc2, adst2, b2, out, N);
}

// Round 4
// 385.208 us; speedup vs baseline: 8.0166x; 1.4365x over previous
//
#include <hip/hip_runtime.h>

#define IN_C 256
#define H1 8
#define C1 32
#define F1 256   // H1*C1
#define OC 16
#define NEG 0.2f

typedef short short8 __attribute__((ext_vector_type(8)));
typedef unsigned short ushort8 __attribute__((ext_vector_type(8)));
typedef float floatx4 __attribute__((ext_vector_type(4)));

__device__ __forceinline__ unsigned short f2bf(float f) {
    unsigned u = __builtin_bit_cast(unsigned, f);
    u = (u + 0x7fffu + ((u >> 16) & 1u)) >> 16;
    return (unsigned short)u;
}
__device__ __forceinline__ float bf2f(unsigned short h) {
    unsigned u = ((unsigned)h) << 16;
    return __builtin_bit_cast(float, u);
}

// ---------------- convert x -> bf16 ----------------
__global__ __launch_bounds__(256) void k_cvt_x(const float* __restrict__ x,
                                               unsigned short* __restrict__ xb, int n4)
{
    int idx = blockIdx.x * 256 + threadIdx.x;
    if (idx >= n4) return;
    float4 v = ((const float4*)x)[idx];
    ushort4 o;
    o.x = f2bf(v.x); o.y = f2bf(v.y); o.z = f2bf(v.z); o.w = f2bf(v.w);
    ((ushort4*)xb)[idx] = o;
}

// ---------------- W1 -> bf16 transposed: w1t[n][k] = W1[k][n] ----------------
__global__ __launch_bounds__(256) void k_w1t(const float* __restrict__ W1,
                                             unsigned short* __restrict__ w1t)
{
    int idx = blockIdx.x * 256 + threadIdx.x;   // 65536
    int n = idx >> 8, k = idx & 255;
    w1t[n * 256 + k] = f2bf(W1[k * 256 + n]);
}

// ---------------- L1 GEMM (bf16 MFMA): xl1b[M,256] = xb[M,256] @ W1 ----------------
// A row-major bf16, B given as w1t[n][k] bf16. Output bf16.
__global__ __launch_bounds__(256) void k_gemm1(const unsigned short* __restrict__ A,
                                               const unsigned short* __restrict__ Bt,
                                               unsigned short* __restrict__ Cb, int M)
{
    __shared__ short As[128][40];   // +8 pad: conflict-free ds_read_b128
    __shared__ short Bs[128][40];
    const int tid  = threadIdx.x;
    const int lane = tid & 63;
    const int w    = tid >> 6;
    const int bm   = blockIdx.x * 128;
    const int bn   = blockIdx.y * 128;
    const int wm   = (w >> 1) * 64;
    const int wn   = (w & 1) * 64;
    const int srow = tid >> 1;          // staging row
    const int soff = (tid & 1) * 16;    // 16 shorts = 32B
    floatx4 acc[4][4] = {};
    for (int k0 = 0; k0 < 256; k0 += 32) {
        __syncthreads();
        // stage A 128x32
        {
            int gr = bm + srow;
            ushort8 v0 = {0,0,0,0,0,0,0,0}, v1 = {0,0,0,0,0,0,0,0};
            if (gr < M) {
                const ushort8* p = (const ushort8*)(A + (size_t)gr * 256 + k0 + soff);
                v0 = p[0]; v1 = p[1];
            }
            *(ushort8*)&As[srow][soff]     = v0;
            *(ushort8*)&As[srow][soff + 8] = v1;
        }
        // stage B 128x32 (from Bt rows)
        {
            const ushort8* p = (const ushort8*)(Bt + (size_t)(bn + srow) * 256 + k0 + soff);
            *(ushort8*)&Bs[srow][soff]     = p[0];
            *(ushort8*)&Bs[srow][soff + 8] = p[1];
        }
        __syncthreads();
        short8 af[4], bf[4];
        const int q8 = (lane >> 4) * 8;
        const int l15 = lane & 15;
#pragma unroll
        for (int i = 0; i < 4; ++i) af[i] = *(const short8*)&As[wm + i * 16 + l15][q8];
#pragma unroll
        for (int j = 0; j < 4; ++j) bf[j] = *(const short8*)&Bs[wn + j * 16 + l15][q8];
#pragma unroll
        for (int i = 0; i < 4; ++i)
#pragma unroll
            for (int j = 0; j < 4; ++j)
                acc[i][j] = __builtin_amdgcn_mfma_f32_16x16x32_bf16(af[i], bf[j], acc[i][j], 0, 0, 0);
    }
    // epilogue: D row = wm+i*16+(lane>>4)*4+reg, col = wn+j*16+(lane&15)
    const int l15 = lane & 15;
    const int rq  = (lane >> 4) * 4;
#pragma unroll
    for (int i = 0; i < 4; ++i) {
#pragma unroll
        for (int reg = 0; reg < 4; ++reg) {
            int gr = bm + wm + i * 16 + rq + reg;
            if (gr < M) {
#pragma unroll
                for (int j = 0; j < 4; ++j)
                    Cb[(size_t)gr * 256 + bn + wn + j * 16 + l15] = f2bf(acc[i][j][reg]);
            }
        }
    }
}

// ---------------- L1 attention coefficients from bf16 xl ----------------
__global__ __launch_bounds__(256) void k_att1(const unsigned short* __restrict__ xl,
                                              const float* __restrict__ att_s,
                                              const float* __restrict__ att_d,
                                              float* __restrict__ asrc,
                                              float* __restrict__ adst, int N)
{
    int idx = blockIdx.x * 256 + threadIdx.x;
    if (idx >= N * H1) return;
    int i = idx >> 3, h = idx & 7;
    const ushort4* xr = (const ushort4*)(xl + (size_t)i * F1 + h * C1);
    const float* s = att_s + h * C1;
    const float* d = att_d + h * C1;
    float s1 = 0.f, s2 = 0.f;
#pragma unroll
    for (int c4 = 0; c4 < 8; ++c4) {
        ushort4 v = xr[c4];
        float f0 = bf2f(v.x), f1 = bf2f(v.y), f2 = bf2f(v.z), f3 = bf2f(v.w);
        int c = c4 * 4;
        s1 += f0 * s[c] + f1 * s[c+1] + f2 * s[c+2] + f3 * s[c+3];
        s2 += f0 * d[c] + f1 * d[c+1] + f2 * d[c+2] + f3 * d[c+3];
    }
    asrc[idx] = s1; adst[idx] = s2;
}

// ---------------- CSR build ----------------
__global__ __launch_bounds__(256) void k_zero(int* __restrict__ p, int n)
{
    int i = blockIdx.x * 256 + threadIdx.x;
    if (i < n) p[i] = 0;
}

__global__ __launch_bounds__(256) void k_hist(const int* __restrict__ ei,
                                              int* __restrict__ cnt, int E)
{
    int e = blockIdx.x * 256 + threadIdx.x;
    if (e < E) atomicAdd(&cnt[ei[E + e]], 1);
}

// single-workgroup exclusive scan, 1024 threads x 4 elems/chunk
__global__ __launch_bounds__(1024) void k_scan(const int* __restrict__ cnt,
                                               int* __restrict__ rp, int N)
{
    __shared__ int wsum[16];
    __shared__ int carry_s;
    int lane = threadIdx.x & 63, wid = threadIdx.x >> 6;
    if (threadIdx.x == 0) { carry_s = 0; rp[0] = 0; }
    __syncthreads();
    for (int base = 0; base < N; base += 4096) {
        int i0 = base + threadIdx.x * 4;
        int v[4];
#pragma unroll
        for (int k = 0; k < 4; ++k) { int i = i0 + k; v[k] = (i < N) ? cnt[i] : 0; }
        int s = v[0] + v[1] + v[2] + v[3];
        int incl = s;
#pragma unroll
        for (int off = 1; off < 64; off <<= 1) {
            int t = __shfl_up(incl, off, 64);
            if (lane >= off) incl += t;
        }
        if (lane == 63) wsum[wid] = incl;
        __syncthreads();
        int wpre = 0;
        for (int ww = 0; ww < wid; ++ww) wpre += wsum[ww];
        int carry = carry_s;
        int run = carry + wpre + incl - s;
#pragma unroll
        for (int k = 0; k < 4; ++k) {
            int i = i0 + k;
            run += v[k];
            if (i < N) rp[i + 1] = run;
        }
        __syncthreads();
        if (threadIdx.x == 1023) carry_s = carry + wpre + incl;
        __syncthreads();
    }
}

__global__ __launch_bounds__(256) void k_scatter(const int* __restrict__ ei,
                                                 const int* __restrict__ rp,
                                                 int* __restrict__ cur,
                                                 int* __restrict__ ssrc, int E)
{
    int e = blockIdx.x * 256 + threadIdx.x;
    if (e >= E) return;
    int s = ei[e];
    int d = ei[E + e];
    int pos = rp[d] + atomicAdd(&cur[d], 1);
    ssrc[pos] = s;
}

// ---------------- L1 gather (bf16 rows, 4x unrolled) ----------------
__global__ __launch_bounds__(256) void k_gather1(const int* __restrict__ rp,
                                                 const int* __restrict__ ssrc,
                                                 const unsigned short* __restrict__ xl,
                                                 const float* __restrict__ asrc,
                                                 const float* __restrict__ adst,
                                                 const float* __restrict__ bias,
                                                 unsigned short* __restrict__ hout, int N)
{
    int lane = threadIdx.x & 63;
    int node = blockIdx.x * 4 + (threadIdx.x >> 6);
    if (node >= N) return;
    int h  = lane >> 3;
    int cb = lane * 4;
    float ad = adst[(size_t)node * H1 + h];
    float e = asrc[(size_t)node * H1 + h] + ad;
    e = e >= 0.f ? e : NEG * e;
    float w = __expf(e);
    ushort4 xv = *(const ushort4*)(xl + (size_t)node * F1 + cb);
    float ax = w * bf2f(xv.x), ay = w * bf2f(xv.y), az = w * bf2f(xv.z), aw = w * bf2f(xv.w);
    float den = w;
    int jb = rp[node], je = rp[node + 1];
    int j = jb;
    for (; j + 4 <= je; j += 4) {
        int s0 = ssrc[j], s1 = ssrc[j+1], s2 = ssrc[j+2], s3 = ssrc[j+3];
        float e0 = asrc[(size_t)s0 * H1 + h] + ad;
        float e1 = asrc[(size_t)s1 * H1 + h] + ad;
        float e2 = asrc[(size_t)s2 * H1 + h] + ad;
        float e3 = asrc[(size_t)s3 * H1 + h] + ad;
        ushort4 r0 = *(const ushort4*)(xl + (size_t)s0 * F1 + cb);
        ushort4 r1 = *(const ushort4*)(xl + (size_t)s1 * F1 + cb);
        ushort4 r2 = *(const ushort4*)(xl + (size_t)s2 * F1 + cb);
        ushort4 r3 = *(const ushort4*)(xl + (size_t)s3 * F1 + cb);
        e0 = e0 >= 0.f ? e0 : NEG * e0;  float w0 = __expf(e0);
        e1 = e1 >= 0.f ? e1 : NEG * e1;  float w1 = __expf(e1);
        e2 = e2 >= 0.f ? e2 : NEG * e2;  float w2 = __expf(e2);
        e3 = e3 >= 0.f ? e3 : NEG * e3;  float w3 = __expf(e3);
        den += w0 + w1 + w2 + w3;
        ax += w0*bf2f(r0.x) + w1*bf2f(r1.x) + w2*bf2f(r2.x) + w3*bf2f(r3.x);
        ay += w0*bf2f(r0.y) + w1*bf2f(r1.y) + w2*bf2f(r2.y) + w3*bf2f(r3.y);
        az += w0*bf2f(r0.z) + w1*bf2f(r1.z) + w2*bf2f(r2.z) + w3*bf2f(r3.z);
        aw += w0*bf2f(r0.w) + w1*bf2f(r1.w) + w2*bf2f(r2.w) + w3*bf2f(r3.w);
    }
    for (; j < je; ++j) {
        int s = ssrc[j];
        float ev = asrc[(size_t)s * H1 + h] + ad;
        ev = ev >= 0.f ? ev : NEG * ev;
        float wv = __expf(ev);
        ushort4 sv = *(const ushort4*)(xl + (size_t)s * F1 + cb);
        ax += wv * bf2f(sv.x); ay += wv * bf2f(sv.y);
        az += wv * bf2f(sv.z); aw += wv * bf2f(sv.w);
        den += wv;
    }
    float inv = 1.f / (den + 1e-16f);
    float4 bv = *(const float4*)(bias + cb);
    ushort4 o;
    o.x = f2bf(fmaxf(ax * inv + bv.x, 0.f));
    o.y = f2bf(fmaxf(ay * inv + bv.y, 0.f));
    o.z = f2bf(fmaxf(az * inv + bv.z, 0.f));
    o.w = f2bf(fmaxf(aw * inv + bv.w, 0.f));
    *(ushort4*)(hout + (size_t)node * F1 + cb) = o;
}

// ---------------- L2 GEMM (bf16 h in) + fused att2 epilogue ----------------
__global__ __launch_bounds__(256) void k_gemm2(const unsigned short* __restrict__ Hm,
                                               const float* __restrict__ W2,
                                               const float* __restrict__ as2,
                                               const float* __restrict__ ad2,
                                               float* __restrict__ xl2,
                                               float* __restrict__ asrc,
                                               float* __restrict__ adst, int N)
{
    __shared__ float Ws[F1 * OC];   // 16 KB
    __shared__ float Hs[16 * F1];   // 16 KB
    int tid = threadIdx.x;
    int base = blockIdx.x * 16;
    for (int idx = tid; idx < F1 * OC; idx += 256) Ws[idx] = W2[idx];
    for (int idx = tid; idx < 16 * F1; idx += 256) {
        int r = idx >> 8, k = idx & 255;
        int gr = base + r;
        Hs[idx] = (gr < N) ? bf2f(Hm[(size_t)gr * F1 + k]) : 0.f;
    }
    __syncthreads();
    int r = tid >> 4, c = tid & 15;
    float acc = 0.f;
#pragma unroll 8
    for (int k = 0; k < F1; ++k) acc += Hs[r * F1 + k] * Ws[k * OC + c];
    int gr = base + r;
    float s1 = acc * as2[c], s2 = acc * ad2[c];
#pragma unroll
    for (int o = 1; o < 16; o <<= 1) { s1 += __shfl_xor(s1, o, 16); s2 += __shfl_xor(s2, o, 16); }
    if (gr < N) {
        xl2[(size_t)gr * OC + c] = acc;
        if (c == 0) { asrc[gr] = s1; adst[gr] = s2; }
    }
}

// ---------------- L2 gather (4x unrolled) + log_softmax ----------------
__global__ __launch_bounds__(256) void k_gather2(const int* __restrict__ rp,
                                                 const int* __restrict__ ssrc,
                                                 const float* __restrict__ xl2,
                                                 const float* __restrict__ asrc,
                                                 const float* __restrict__ adst,
                                                 const float* __restrict__ bias,
                                                 float* __restrict__ out, int N)
{
    int sub  = threadIdx.x & 15;
    int node = blockIdx.x * 16 + (threadIdx.x >> 4);
    if (node >= N) return;
    float ad = adst[node];
    float e = asrc[node] + ad;
    e = e >= 0.f ? e : NEG * e;
    float w = __expf(e);
    float acc = w * xl2[(size_t)node * OC + sub];
    float den = w;
    int jb = rp[node], je = rp[node + 1];
    int j = jb;
    for (; j + 4 <= je; j += 4) {
        int s0 = ssrc[j], s1i = ssrc[j+1], s2i = ssrc[j+2], s3i = ssrc[j+3];
        float e0 = asrc[s0] + ad, e1 = asrc[s1i] + ad, e2 = asrc[s2i] + ad, e3 = asrc[s3i] + ad;
        float v0 = xl2[(size_t)s0 * OC + sub];
        float v1 = xl2[(size_t)s1i * OC + sub];
        float v2 = xl2[(size_t)s2i * OC + sub];
        float v3 = xl2[(size_t)s3i * OC + sub];
        e0 = e0 >= 0.f ? e0 : NEG * e0;  float w0 = __expf(e0);
        e1 = e1 >= 0.f ? e1 : NEG * e1;  float w1 = __expf(e1);
        e2 = e2 >= 0.f ? e2 : NEG * e2;  float w2 = __expf(e2);
        e3 = e3 >= 0.f ? e3 : NEG * e3;  float w3 = __expf(e3);
        den += w0 + w1 + w2 + w3;
        acc += w0 * v0 + w1 * v1 + w2 * v2 + w3 * v3;
    }
    for (; j < je; ++j) {
        int s = ssrc[j];
        float ev = asrc[s] + ad;
        ev = ev >= 0.f ? ev : NEG * ev;
        float wv = __expf(ev);
        acc += wv * xl2[(size_t)s * OC + sub];
        den += wv;
    }
    float v = acc / (den + 1e-16f) + bias[sub];
    float m = v;
#pragma unroll
    for (int o = 1; o < 16; o <<= 1) m = fmaxf(m, __shfl_xor(m, o, 16));
    float ex = __expf(v - m);
    float ss = ex;
#pragma unroll
    for (int o = 1; o < 16; o <<= 1) ss += __shfl_xor(ss, o, 16);
    out[(size_t)node * OC + sub] = v - m - logf(ss);
}

extern "C" void kernel_launch(void* const* d_in, const int* in_sizes, int n_in,
                              void* d_out, int out_size, void* d_ws, size_t ws_size,
                              hipStream_t stream)
{
    const float* x   = (const float*)d_in[0];
    const int*   ei  = (const int*)d_in[1];
    const float* W1  = (const float*)d_in[2];
    const float* as1 = (const float*)d_in[3];
    const float* ad1 = (const float*)d_in[4];
    const float* b1  = (const float*)d_in[5];
    const float* W2  = (const float*)d_in[6];
    const float* as2 = (const float*)d_in[7];
    const float* ad2 = (const float*)d_in[8];
    const float* b2  = (const float*)d_in[9];
    float* out = (float*)d_out;

    const int N = in_sizes[0] / IN_C;   // 50000
    const int E = in_sizes[1] / 2;      // 800000

    char* base = (char*)d_ws;
    unsigned short* xb   = (unsigned short*)base;                      // N*256 bf16
    unsigned short* xl1b = xb + (size_t)N * F1;                        // N*256 bf16
    unsigned short* hb   = xl1b + (size_t)N * F1;                      // N*256 bf16
    unsigned short* w1t  = hb + (size_t)N * F1;                        // 256*256 bf16
    float* asrc1 = (float*)(w1t + 256 * 256);                          // N*H1
    float* adst1 = asrc1 + (size_t)N * H1;                             // N*H1
    float* xl2   = adst1 + (size_t)N * H1;                             // N*OC
    float* asrc2 = xl2 + (size_t)N * OC;                               // N
    float* adst2 = asrc2 + N;                                         // N
    int*   rp    = (int*)(adst2 + N);                                  // N+1
    int*   cnt   = rp + (N + 1);                                       // N
    int*   cur   = cnt + N;                                            // N
    int*   ssrc  = cur + N;                                            // E

    // ---- CSR build ----
    k_zero<<<(2 * N + 255) / 256, 256, 0, stream>>>(cnt, 2 * N);
    k_hist<<<(E + 255) / 256, 256, 0, stream>>>(ei, cnt, E);
    k_scan<<<1, 1024, 0, stream>>>(cnt, rp, N);
    k_scatter<<<(E + 255) / 256, 256, 0, stream>>>(ei, rp, cur, ssrc, E);

    // ---- conversions ----
    k_cvt_x<<<(N * 64 + 255) / 256, 256, 0, stream>>>(x, xb, N * 64);
    k_w1t<<<256, 256, 0, stream>>>(W1, w1t);

    // ---- layer 1 ----
    k_gemm1<<<dim3((N + 127) / 128, 2), 256, 0, stream>>>(xb, w1t, xl1b, N);
    k_att1<<<(N * H1 + 255) / 256, 256, 0, stream>>>(xl1b, as1, ad1, asrc1, adst1, N);
    k_gather1<<<(N + 3) / 4, 256, 0, stream>>>(rp, ssrc, xl1b, asrc1, adst1, b1, hb, N);

    // ---- layer 2 ----
    k_gemm2<<<(N + 15) / 16, 256, 0, stream>>>(hb, W2, as2, ad2, xl2, asrc2, adst2, N);
    k_gather2<<<(N + 15) / 16, 256, 0, stream>>>(rp, ssrc, xl2, asrc2, adst2, b2, out, N);
}

// Round 5
// 338.487 us; speedup vs baseline: 9.1231x; 1.1380x over previous
//
#include <hip/hip_runtime.h>

#define IN_C 256
#define H1 8
#define C1 32
#define F1 256   // H1*C1
#define OC 16
#define NEG 0.2f

typedef short short8 __attribute__((ext_vector_type(8)));
typedef unsigned short ushort8 __attribute__((ext_vector_type(8)));
typedef float floatx4 __attribute__((ext_vector_type(4)));

__device__ __forceinline__ unsigned short f2bf(float f) {
    unsigned u = __builtin_bit_cast(unsigned, f);
    u = (u + 0x7fffu + ((u >> 16) & 1u)) >> 16;
    return (unsigned short)u;
}
__device__ __forceinline__ float bf2f(unsigned short h) {
    unsigned u = ((unsigned)h) << 16;
    return __builtin_bit_cast(float, u);
}

// ---------------- convert x -> bf16 ----------------
__global__ __launch_bounds__(256) void k_cvt_x(const float* __restrict__ x,
                                               unsigned short* __restrict__ xb, int n4)
{
    int idx = blockIdx.x * 256 + threadIdx.x;
    if (idx >= n4) return;
    float4 v = ((const float4*)x)[idx];
    ushort4 o;
    o.x = f2bf(v.x); o.y = f2bf(v.y); o.z = f2bf(v.z); o.w = f2bf(v.w);
    ((ushort4*)xb)[idx] = o;
}

// ---------------- W1,W2 -> bf16 transposed ----------------
__global__ __launch_bounds__(256) void k_wcvt(const float* __restrict__ W1,
                                              const float* __restrict__ W2,
                                              unsigned short* __restrict__ w1t,
                                              unsigned short* __restrict__ w2t)
{
    int idx = blockIdx.x * 256 + threadIdx.x;   // 65536 + 4096
    if (idx < 65536) {
        int n = idx >> 8, k = idx & 255;
        w1t[n * 256 + k] = f2bf(W1[k * 256 + n]);
    } else if (idx < 65536 + 4096) {
        int r = idx - 65536;
        int n = r >> 8, k = r & 255;        // n<16, k<256
        w2t[n * 256 + k] = f2bf(W2[k * 16 + n]);
    }
}

// ---------------- L1 GEMM (bf16 MFMA): xl1b[M,256] = xb[M,256] @ W1 ----------------
__global__ __launch_bounds__(256) void k_gemm1(const unsigned short* __restrict__ A,
                                               const unsigned short* __restrict__ Bt,
                                               unsigned short* __restrict__ Cb, int M)
{
    __shared__ short As[128][40];   // +8 pad: conflict-free ds_read_b128
    __shared__ short Bs[128][40];
    const int tid  = threadIdx.x;
    const int lane = tid & 63;
    const int w    = tid >> 6;
    const int bm   = blockIdx.x * 128;
    const int bn   = blockIdx.y * 128;
    const int wm   = (w >> 1) * 64;
    const int wn   = (w & 1) * 64;
    const int srow = tid >> 1;          // staging row
    const int soff = (tid & 1) * 16;    // 16 shorts = 32B
    floatx4 acc[4][4] = {};
    for (int k0 = 0; k0 < 256; k0 += 32) {
        __syncthreads();
        {
            int gr = bm + srow;
            ushort8 v0 = {0,0,0,0,0,0,0,0}, v1 = {0,0,0,0,0,0,0,0};
            if (gr < M) {
                const ushort8* p = (const ushort8*)(A + (size_t)gr * 256 + k0 + soff);
                v0 = p[0]; v1 = p[1];
            }
            *(ushort8*)&As[srow][soff]     = v0;
            *(ushort8*)&As[srow][soff + 8] = v1;
        }
        {
            const ushort8* p = (const ushort8*)(Bt + (size_t)(bn + srow) * 256 + k0 + soff);
            *(ushort8*)&Bs[srow][soff]     = p[0];
            *(ushort8*)&Bs[srow][soff + 8] = p[1];
        }
        __syncthreads();
        short8 af[4], bf[4];
        const int q8 = (lane >> 4) * 8;
        const int l15 = lane & 15;
#pragma unroll
        for (int i = 0; i < 4; ++i) af[i] = *(const short8*)&As[wm + i * 16 + l15][q8];
#pragma unroll
        for (int j = 0; j < 4; ++j) bf[j] = *(const short8*)&Bs[wn + j * 16 + l15][q8];
#pragma unroll
        for (int i = 0; i < 4; ++i)
#pragma unroll
            for (int j = 0; j < 4; ++j)
                acc[i][j] = __builtin_amdgcn_mfma_f32_16x16x32_bf16(af[i], bf[j], acc[i][j], 0, 0, 0);
    }
    const int l15 = lane & 15;
    const int rq  = (lane >> 4) * 4;
#pragma unroll
    for (int i = 0; i < 4; ++i) {
#pragma unroll
        for (int reg = 0; reg < 4; ++reg) {
            int gr = bm + wm + i * 16 + rq + reg;
            if (gr < M) {
#pragma unroll
                for (int j = 0; j < 4; ++j)
                    Cb[(size_t)gr * 256 + bn + wn + j * 16 + l15] = f2bf(acc[i][j][reg]);
            }
        }
    }
}

// ---------------- L1 attention coefficients from bf16 xl ----------------
__global__ __launch_bounds__(256) void k_att1(const unsigned short* __restrict__ xl,
                                              const float* __restrict__ att_s,
                                              const float* __restrict__ att_d,
                                              float* __restrict__ asrc,
                                              float* __restrict__ adst, int N)
{
    int idx = blockIdx.x * 256 + threadIdx.x;
    if (idx >= N * H1) return;
    int i = idx >> 3, h = idx & 7;
    const ushort4* xr = (const ushort4*)(xl + (size_t)i * F1 + h * C1);
    const float* s = att_s + h * C1;
    const float* d = att_d + h * C1;
    float s1 = 0.f, s2 = 0.f;
#pragma unroll
    for (int c4 = 0; c4 < 8; ++c4) {
        ushort4 v = xr[c4];
        float f0 = bf2f(v.x), f1 = bf2f(v.y), f2 = bf2f(v.z), f3 = bf2f(v.w);
        int c = c4 * 4;
        s1 += f0 * s[c] + f1 * s[c+1] + f2 * s[c+2] + f3 * s[c+3];
        s2 += f0 * d[c] + f1 * d[c+1] + f2 * d[c+2] + f3 * d[c+3];
    }
    asrc[idx] = s1; adst[idx] = s2;
}

// ---------------- CSR build ----------------
__global__ __launch_bounds__(256) void k_hist(const int* __restrict__ ei,
                                              int* __restrict__ cnt, int E)
{
    int e = blockIdx.x * 256 + threadIdx.x;
    if (e < E) atomicAdd(&cnt[ei[E + e]], 1);
}

// phase A: per-block inclusive scan of cnt -> rp[i+1] (pre-offset), block sums -> bsum
__global__ __launch_bounds__(256) void k_scan_a(const int* __restrict__ cnt,
                                                int* __restrict__ rp,
                                                int* __restrict__ bsum, int N)
{
    __shared__ int ws4[4];
    int t = threadIdx.x, lane = t & 63, wid = t >> 6;
    int i = blockIdx.x * 256 + t;
    int v = (i < N) ? cnt[i] : 0;
    int incl = v;
#pragma unroll
    for (int off = 1; off < 64; off <<= 1) {
        int tv = __shfl_up(incl, off, 64);
        if (lane >= off) incl += tv;
    }
    if (lane == 63) ws4[wid] = incl;
    __syncthreads();
    int add = 0;
    for (int w = 0; w < wid; ++w) add += ws4[w];
    incl += add;
    if (i < N) rp[i + 1] = incl;
    if (t == 255) bsum[blockIdx.x] = incl;
}

// phase B: exclusive scan of bsum (up to 1024 blocks) -> boff
__global__ __launch_bounds__(256) void k_scan_b(const int* __restrict__ bsum,
                                                int* __restrict__ boff, int NB)
{
    __shared__ int ws4[4];
    int t = threadIdx.x, lane = t & 63, wid = t >> 6;
    int i0 = t * 4;
    int v[4];
#pragma unroll
    for (int k = 0; k < 4; ++k) { int i = i0 + k; v[k] = (i < NB) ? bsum[i] : 0; }
    int s = v[0] + v[1] + v[2] + v[3];
    int incl = s;
#pragma unroll
    for (int off = 1; off < 64; off <<= 1) {
        int tv = __shfl_up(incl, off, 64);
        if (lane >= off) incl += tv;
    }
    if (lane == 63) ws4[wid] = incl;
    __syncthreads();
    int wpre = 0;
    for (int w = 0; w < wid; ++w) wpre += ws4[w];
    int run = wpre + incl - s;
#pragma unroll
    for (int k = 0; k < 4; ++k) {
        int i = i0 + k;
        if (i < NB) boff[i] = run;
        run += v[k];
    }
}

// phase C: add block offsets; set rp[0]=0
__global__ __launch_bounds__(256) void k_scan_c(int* __restrict__ rp,
                                                const int* __restrict__ boff, int N)
{
    int i = blockIdx.x * 256 + threadIdx.x;
    if (i < N) rp[i + 1] += boff[blockIdx.x];
    if (i == 0) rp[0] = 0;
}

__global__ __launch_bounds__(256) void k_scatter(const int* __restrict__ ei,
                                                 int* __restrict__ cur,
                                                 int* __restrict__ ssrc, int E)
{
    int e = blockIdx.x * 256 + threadIdx.x;
    if (e >= E) return;
    int s = ei[e];
    int d = ei[E + e];
    int pos = atomicAdd(&cur[d], 1);
    ssrc[pos] = s;
}

// ---------------- L1 gather (bf16 rows, 4x unrolled) ----------------
__global__ __launch_bounds__(256) void k_gather1(const int* __restrict__ rp,
                                                 const int* __restrict__ ssrc,
                                                 const unsigned short* __restrict__ xl,
                                                 const float* __restrict__ asrc,
                                                 const float* __restrict__ adst,
                                                 const float* __restrict__ bias,
                                                 unsigned short* __restrict__ hout, int N)
{
    int lane = threadIdx.x & 63;
    int node = blockIdx.x * 4 + (threadIdx.x >> 6);
    if (node >= N) return;
    int h  = lane >> 3;
    int cb = lane * 4;
    float ad = adst[(size_t)node * H1 + h];
    float e = asrc[(size_t)node * H1 + h] + ad;
    e = e >= 0.f ? e : NEG * e;
    float w = __expf(e);
    ushort4 xv = *(const ushort4*)(xl + (size_t)node * F1 + cb);
    float ax = w * bf2f(xv.x), ay = w * bf2f(xv.y), az = w * bf2f(xv.z), aw = w * bf2f(xv.w);
    float den = w;
    int jb = rp[node], je = rp[node + 1];
    int j = jb;
    for (; j + 4 <= je; j += 4) {
        int s0 = ssrc[j], s1 = ssrc[j+1], s2 = ssrc[j+2], s3 = ssrc[j+3];
        float e0 = asrc[(size_t)s0 * H1 + h] + ad;
        float e1 = asrc[(size_t)s1 * H1 + h] + ad;
        float e2 = asrc[(size_t)s2 * H1 + h] + ad;
        float e3 = asrc[(size_t)s3 * H1 + h] + ad;
        ushort4 r0 = *(const ushort4*)(xl + (size_t)s0 * F1 + cb);
        ushort4 r1 = *(const ushort4*)(xl + (size_t)s1 * F1 + cb);
        ushort4 r2 = *(const ushort4*)(xl + (size_t)s2 * F1 + cb);
        ushort4 r3 = *(const ushort4*)(xl + (size_t)s3 * F1 + cb);
        e0 = e0 >= 0.f ? e0 : NEG * e0;  float w0 = __expf(e0);
        e1 = e1 >= 0.f ? e1 : NEG * e1;  float w1 = __expf(e1);
        e2 = e2 >= 0.f ? e2 : NEG * e2;  float w2 = __expf(e2);
        e3 = e3 >= 0.f ? e3 : NEG * e3;  float w3 = __expf(e3);
        den += w0 + w1 + w2 + w3;
        ax += w0*bf2f(r0.x) + w1*bf2f(r1.x) + w2*bf2f(r2.x) + w3*bf2f(r3.x);
        ay += w0*bf2f(r0.y) + w1*bf2f(r1.y) + w2*bf2f(r2.y) + w3*bf2f(r3.y);
        az += w0*bf2f(r0.z) + w1*bf2f(r1.z) + w2*bf2f(r2.z) + w3*bf2f(r3.z);
        aw += w0*bf2f(r0.w) + w1*bf2f(r1.w) + w2*bf2f(r2.w) + w3*bf2f(r3.w);
    }
    for (; j < je; ++j) {
        int s = ssrc[j];
        float ev = asrc[(size_t)s * H1 + h] + ad;
        ev = ev >= 0.f ? ev : NEG * ev;
        float wv = __expf(ev);
        ushort4 sv = *(const ushort4*)(xl + (size_t)s * F1 + cb);
        ax += wv * bf2f(sv.x); ay += wv * bf2f(sv.y);
        az += wv * bf2f(sv.z); aw += wv * bf2f(sv.w);
        den += wv;
    }
    float inv = 1.f / (den + 1e-16f);
    float4 bv = *(const float4*)(bias + cb);
    ushort4 o;
    o.x = f2bf(fmaxf(ax * inv + bv.x, 0.f));
    o.y = f2bf(fmaxf(ay * inv + bv.y, 0.f));
    o.z = f2bf(fmaxf(az * inv + bv.z, 0.f));
    o.w = f2bf(fmaxf(aw * inv + bv.w, 0.f));
    *(ushort4*)(hout + (size_t)node * F1 + cb) = o;
}

// ---------------- L2 GEMM (bf16 MFMA, no LDS) + fused att2 epilogue ----------------
// xl2b[M,16] = hb[M,256] @ W2, W2 given transposed bf16 w2t[16][256].
__global__ __launch_bounds__(256) void k_gemm2(const unsigned short* __restrict__ Hm,
                                               const unsigned short* __restrict__ W2t,
                                               const float* __restrict__ as2,
                                               const float* __restrict__ ad2,
                                               unsigned short* __restrict__ xl2b,
                                               float* __restrict__ asrc,
                                               float* __restrict__ adst, int N)
{
    const int lane = threadIdx.x & 63;
    const int wid  = threadIdx.x >> 6;
    const int rowbase = blockIdx.x * 64 + wid * 16;
    const int col = lane & 15;
    const int q8  = (lane >> 4) * 8;
    const int m   = rowbase + col;            // A-frag row
    const bool mv = m < N;
    const unsigned short* arow = Hm + (size_t)m * 256 + q8;
    const unsigned short* brow = W2t + (size_t)col * 256 + q8;
    floatx4 acc = {0.f, 0.f, 0.f, 0.f};
#pragma unroll
    for (int t = 0; t < 8; ++t) {
        short8 af = {0,0,0,0,0,0,0,0};
        if (mv) af = *(const short8*)(arow + t * 32);
        short8 bf = *(const short8*)(brow + t * 32);
        acc = __builtin_amdgcn_mfma_f32_16x16x32_bf16(af, bf, acc, 0, 0, 0);
    }
    float s_as = as2[col], s_ad = ad2[col];
    const int rq = (lane >> 4) * 4;
#pragma unroll
    for (int reg = 0; reg < 4; ++reg) {
        int row = rowbase + rq + reg;
        float v = acc[reg];
        float s1 = v * s_as, s2 = v * s_ad;
#pragma unroll
        for (int o = 1; o < 16; o <<= 1) { s1 += __shfl_xor(s1, o, 16); s2 += __shfl_xor(s2, o, 16); }
        if (row < N) {
            xl2b[(size_t)row * OC + col] = f2bf(v);
            if (col == 0) { asrc[row] = s1; adst[row] = s2; }
        }
    }
}

// ---------------- L2 gather (bf16 rows, 4x unrolled) + log_softmax ----------------
__global__ __launch_bounds__(256) void k_gather2(const int* __restrict__ rp,
                                                 const int* __restrict__ ssrc,
                                                 const unsigned short* __restrict__ xl2b,
                                                 const float* __restrict__ asrc,
                                                 const float* __restrict__ adst,
                                                 const float* __restrict__ bias,
                                                 float* __restrict__ out, int N)
{
    int sub  = threadIdx.x & 15;
    int node = blockIdx.x * 16 + (threadIdx.x >> 4);
    if (node >= N) return;
    float ad = adst[node];
    float e = asrc[node] + ad;
    e = e >= 0.f ? e : NEG * e;
    float w = __expf(e);
    float acc = w * bf2f(xl2b[(size_t)node * OC + sub]);
    float den = w;
    int jb = rp[node], je = rp[node + 1];
    int j = jb;
    for (; j + 4 <= je; j += 4) {
        int s0 = ssrc[j], s1i = ssrc[j+1], s2i = ssrc[j+2], s3i = ssrc[j+3];
        float e0 = asrc[s0] + ad, e1 = asrc[s1i] + ad, e2 = asrc[s2i] + ad, e3 = asrc[s3i] + ad;
        float v0 = bf2f(xl2b[(size_t)s0 * OC + sub]);
        float v1 = bf2f(xl2b[(size_t)s1i * OC + sub]);
        float v2 = bf2f(xl2b[(size_t)s2i * OC + sub]);
        float v3 = bf2f(xl2b[(size_t)s3i * OC + sub]);
        e0 = e0 >= 0.f ? e0 : NEG * e0;  float w0 = __expf(e0);
        e1 = e1 >= 0.f ? e1 : NEG * e1;  float w1 = __expf(e1);
        e2 = e2 >= 0.f ? e2 : NEG * e2;  float w2 = __expf(e2);
        e3 = e3 >= 0.f ? e3 : NEG * e3;  float w3 = __expf(e3);
        den += w0 + w1 + w2 + w3;
        acc += w0 * v0 + w1 * v1 + w2 * v2 + w3 * v3;
    }
    for (; j < je; ++j) {
        int s = ssrc[j];
        float ev = asrc[s] + ad;
        ev = ev >= 0.f ? ev : NEG * ev;
        float wv = __expf(ev);
        acc += wv * bf2f(xl2b[(size_t)s * OC + sub]);
        den += wv;
    }
    float v = acc / (den + 1e-16f) + bias[sub];
    float m = v;
#pragma unroll
    for (int o = 1; o < 16; o <<= 1) m = fmaxf(m, __shfl_xor(m, o, 16));
    float ex = __expf(v - m);
    float ss = ex;
#pragma unroll
    for (int o = 1; o < 16; o <<= 1) ss += __shfl_xor(ss, o, 16);
    out[(size_t)node * OC + sub] = v - m - logf(ss);
}

extern "C" void kernel_launch(void* const* d_in, const int* in_sizes, int n_in,
                              void* d_out, int out_size, void* d_ws, size_t ws_size,
                              hipStream_t stream)
{
    const float* x   = (const float*)d_in[0];
    const int*   ei  = (const int*)d_in[1];
    const float* W1  = (const float*)d_in[2];
    const float* as1 = (const float*)d_in[3];
    const float* ad1 = (const float*)d_in[4];
    const float* b1  = (const float*)d_in[5];
    const float* W2  = (const float*)d_in[6];
    const float* as2 = (const float*)d_in[7];
    const float* ad2 = (const float*)d_in[8];
    const float* b2  = (const float*)d_in[9];
    float* out = (float*)d_out;

    const int N = in_sizes[0] / IN_C;   // 50000
    const int E = in_sizes[1] / 2;      // 800000
    const int NB = (N + 255) / 256;     // 196 scan blocks

    char* base = (char*)d_ws;
    unsigned short* xb   = (unsigned short*)base;                      // N*256 bf16
    unsigned short* xl1b = xb + (size_t)N * F1;                        // N*256 bf16
    unsigned short* hb   = xl1b + (size_t)N * F1;                      // N*256 bf16
    unsigned short* w1t  = hb + (size_t)N * F1;                        // 256*256 bf16
    unsigned short* w2t  = w1t + 256 * 256;                            // 16*256 bf16
    unsigned short* xl2b = w2t + 16 * 256;                             // N*16 bf16
    float* asrc1 = (float*)(xl2b + (size_t)N * OC);                    // N*H1
    float* adst1 = asrc1 + (size_t)N * H1;                             // N*H1
    float* asrc2 = adst1 + (size_t)N * H1;                             // N
    float* adst2 = asrc2 + N;                                          // N
    int*   rp    = (int*)(adst2 + N);                                  // N+1
    int*   cnt   = rp + (N + 1);                                       // N
    int*   cur   = cnt + N;                                            // N
    int*   bsum  = cur + N;                                            // 1024
    int*   boff  = bsum + 1024;                                        // 1024
    int*   ssrc  = boff + 1024;                                        // E

    // ---- CSR build ----
    hipMemsetAsync(cnt, 0, (size_t)N * sizeof(int), stream);
    k_hist<<<(E + 255) / 256, 256, 0, stream>>>(ei, cnt, E);
    k_scan_a<<<NB, 256, 0, stream>>>(cnt, rp, bsum, N);
    k_scan_b<<<1, 256, 0, stream>>>(bsum, boff, NB);
    k_scan_c<<<NB, 256, 0, stream>>>(rp, boff, N);
    hipMemcpyAsync(cur, rp, (size_t)N * sizeof(int), hipMemcpyDeviceToDevice, stream);
    k_scatter<<<(E + 255) / 256, 256, 0, stream>>>(ei, cur, ssrc, E);

    // ---- conversions ----
    k_cvt_x<<<(N * 64 + 255) / 256, 256, 0, stream>>>(x, xb, N * 64);
    k_wcvt<<<(65536 + 4096) / 256, 256, 0, stream>>>(W1, W2, w1t, w2t);

    // ---- layer 1 ----
    k_gemm1<<<dim3((N + 127) / 128, 2), 256, 0, stream>>>(xb, w1t, xl1b, N);
    k_att1<<<(N * H1 + 255) / 256, 256, 0, stream>>>(xl1b, as1, ad1, asrc1, adst1, N);
    k_gather1<<<(N + 3) / 4, 256, 0, stream>>>(rp, ssrc, xl1b, asrc1, adst1, b1, hb, N);

    // ---- layer 2 ----
    k_gemm2<<<(N + 63) / 64, 256, 0, stream>>>(hb, w2t, as2, ad2, xl2b, asrc2, adst2, N);
    k_gather2<<<(N + 15) / 16, 256, 0, stream>>>(rp, ssrc, xl2b, asrc2, adst2, b2, out, N);
}